// Round 15
// baseline (88.914 us; speedup 1.0000x reference)
//
#include <hip/hip_runtime.h>

constexpr int NSAMP = 32768;
constexpr int DIM   = 2048;
constexpr int NCLS  = 512;
constexpr double EPS = 1e-6;
constexpr int NSLICE = 2;              // 2 slices x 1024 cols = 2048
constexpr int NPART  = NSLICE * NCLS;  // 1024 partial slots
constexpr int CAPL   = 256;            // LDS bucket capacity; max class count ~95

// ws layout (byte offsets):
//   0      : double partQ[1024]       (8192 B)
//   8192   : double partT[1024]       (8192 B)

// 1024 single-wave blocks; block = (class via hash, 1024-col slice).
// NO prep kernels: each block scans the 128 KB label array itself (int4
// loads, L2-resident after first touch; ~64 matches appended to LDS via
// block-local LDS atomics - order-invariant sums, so order doesn't matter).
// Gather: thread owns 16 cols as 4 float4s (+0/+256/+512/+768); wave reads
// 1024 contiguous cols = 4 KB per row. Whole-class rows in registers; zero
// global atomics; 2 graph nodes total.
__global__ void __launch_bounds__(64) k_main(const float* __restrict__ x,
                                             const int* __restrict__ label,
                                             double* __restrict__ partQ,
                                             double* __restrict__ partT) {
    const int b  = blockIdx.x;
    const int q0 = b >> 1;                       // 0..511
    const int s  = b & 1;                        // slice
    const int c  = (q0 * 331 + s * 57) & 511;    // bijective per slice

    __shared__ int idx_lds[CAPL];
    __shared__ int cnt_lds;
    if (threadIdx.x == 0) cnt_lds = 0;
    __syncthreads();

    // --- self-scan: find this class's row indices ---
    const int4* lab4 = reinterpret_cast<const int4*>(label);
    #pragma unroll 4
    for (int it = 0; it < NSAMP / 256; ++it) {
        const int4 L  = lab4[it * 64 + threadIdx.x];
        const int base = it * 256 + threadIdx.x * 4;
        if (L.x == c) { int p = atomicAdd(&cnt_lds, 1); if (p < CAPL) idx_lds[p] = base; }
        if (L.y == c) { int p = atomicAdd(&cnt_lds, 1); if (p < CAPL) idx_lds[p] = base + 1; }
        if (L.z == c) { int p = atomicAdd(&cnt_lds, 1); if (p < CAPL) idx_lds[p] = base + 2; }
        if (L.w == c) { int p = atomicAdd(&cnt_lds, 1); if (p < CAPL) idx_lds[p] = base + 3; }
    }
    __syncthreads();
    const int cnt = min(cnt_lds, CAPL);

    // --- gather: 4 KB/row granule, 4-row unroll (16 KB/wave in flight) ---
    const float* xp = x + s * 1024 + threadIdx.x * 4;

    float4 S0 = {0,0,0,0}, S1 = {0,0,0,0}, S2 = {0,0,0,0}, S3 = {0,0,0,0};
    float Q0 = 0.f, Q1 = 0.f, Q2 = 0.f, Q3 = 0.f;

    int r = 0;
    for (; r + 4 <= cnt; r += 4) {
        float4 v[4][4];
        #pragma unroll
        for (int j = 0; j < 4; ++j) {
            const float* rp = xp + (size_t)idx_lds[r + j] * DIM;
            v[j][0] = *reinterpret_cast<const float4*>(rp);
            v[j][1] = *reinterpret_cast<const float4*>(rp + 256);
            v[j][2] = *reinterpret_cast<const float4*>(rp + 512);
            v[j][3] = *reinterpret_cast<const float4*>(rp + 768);
        }
        #pragma unroll
        for (int j = 0; j < 4; ++j) {
            S0.x += v[j][0].x; S0.y += v[j][0].y; S0.z += v[j][0].z; S0.w += v[j][0].w;
            Q0 += v[j][0].x*v[j][0].x + v[j][0].y*v[j][0].y + v[j][0].z*v[j][0].z + v[j][0].w*v[j][0].w;
            S1.x += v[j][1].x; S1.y += v[j][1].y; S1.z += v[j][1].z; S1.w += v[j][1].w;
            Q1 += v[j][1].x*v[j][1].x + v[j][1].y*v[j][1].y + v[j][1].z*v[j][1].z + v[j][1].w*v[j][1].w;
            S2.x += v[j][2].x; S2.y += v[j][2].y; S2.z += v[j][2].z; S2.w += v[j][2].w;
            Q2 += v[j][2].x*v[j][2].x + v[j][2].y*v[j][2].y + v[j][2].z*v[j][2].z + v[j][2].w*v[j][2].w;
            S3.x += v[j][3].x; S3.y += v[j][3].y; S3.z += v[j][3].z; S3.w += v[j][3].w;
            Q3 += v[j][3].x*v[j][3].x + v[j][3].y*v[j][3].y + v[j][3].z*v[j][3].z + v[j][3].w*v[j][3].w;
        }
    }
    for (; r < cnt; ++r) {
        const float* rp = xp + (size_t)idx_lds[r] * DIM;
        const float4 a  = *reinterpret_cast<const float4*>(rp);
        const float4 b2 = *reinterpret_cast<const float4*>(rp + 256);
        const float4 e  = *reinterpret_cast<const float4*>(rp + 512);
        const float4 f  = *reinterpret_cast<const float4*>(rp + 768);
        S0.x += a.x;  S0.y += a.y;  S0.z += a.z;  S0.w += a.w;
        Q0 += a.x*a.x + a.y*a.y + a.z*a.z + a.w*a.w;
        S1.x += b2.x; S1.y += b2.y; S1.z += b2.z; S1.w += b2.w;
        Q1 += b2.x*b2.x + b2.y*b2.y + b2.z*b2.z + b2.w*b2.w;
        S2.x += e.x;  S2.y += e.y;  S2.z += e.z;  S2.w += e.w;
        Q2 += e.x*e.x + e.y*e.y + e.z*e.z + e.w*e.w;
        S3.x += f.x;  S3.y += f.y;  S3.z += f.z;  S3.w += f.w;
        Q3 += f.x*f.x + f.y*f.y + f.z*f.z + f.w*f.w;
    }

    // distinct columns: square each column-sum separately
    double s2 = (double)S0.x*(double)S0.x + (double)S0.y*(double)S0.y
              + (double)S0.z*(double)S0.z + (double)S0.w*(double)S0.w
              + (double)S1.x*(double)S1.x + (double)S1.y*(double)S1.y
              + (double)S1.z*(double)S1.z + (double)S1.w*(double)S1.w
              + (double)S2.x*(double)S2.x + (double)S2.y*(double)S2.y
              + (double)S2.z*(double)S2.z + (double)S2.w*(double)S2.w
              + (double)S3.x*(double)S3.x + (double)S3.y*(double)S3.y
              + (double)S3.z*(double)S3.z + (double)S3.w*(double)S3.w;
    double q  = (double)(Q0 + Q1 + Q2 + Q3);

    #pragma unroll
    for (int off = 32; off > 0; off >>= 1) {
        q  += __shfl_down(q,  off, 64);
        s2 += __shfl_down(s2, off, 64);
    }
    if (threadIdx.x == 0) {
        const int slot = c * NSLICE + s;
        partQ[slot] = q;
        partT[slot] = (cnt > 0) ? (s2 / (double)cnt) : 0.0;
    }
}

__global__ void __launch_bounds__(256) k_final(const double* __restrict__ partQ,
                                               const double* __restrict__ partT,
                                               float* __restrict__ out) {
    double q = 0.0, t3 = 0.0;
    for (int i = threadIdx.x; i < NPART; i += 256) {
        q  += partQ[i];
        t3 += partT[i];
    }
    __shared__ double sq[256], st[256];
    sq[threadIdx.x] = q;
    st[threadIdx.x] = t3;
    __syncthreads();
    for (int o = 128; o > 0; o >>= 1) {
        if (threadIdx.x < o) {
            sq[threadIdx.x] += sq[threadIdx.x + o];
            st[threadIdx.x] += st[threadIdx.x + o];
        }
        __syncthreads();
    }
    if (threadIdx.x == 0) {
        // loss = (Q - T3)/N + D*eps^2  (the 2*eps linear term cancels exactly)
        out[0] = (float)((sq[0] - st[0]) / (double)NSAMP + (double)DIM * EPS * EPS);
    }
}

extern "C" void kernel_launch(void* const* d_in, const int* in_sizes, int n_in,
                              void* d_out, int out_size, void* d_ws, size_t ws_size,
                              hipStream_t stream) {
    const float* x     = (const float*)d_in[0];
    const int*   label = (const int*)d_in[1];
    float*       out   = (float*)d_out;

    char* ws = (char*)d_ws;
    double* partQ = (double*)(ws + 0);
    double* partT = (double*)(ws + 8192);

    hipLaunchKernelGGL(k_main, dim3(NSLICE * NCLS), dim3(64), 0, stream,
                       x, label, partQ, partT);
    hipLaunchKernelGGL(k_final, dim3(1), dim3(256), 0, stream, partQ, partT, out);
}

// Round 16
// 65.533 us; speedup vs baseline: 1.3568x; 1.3568x over previous
//
#include <hip/hip_runtime.h>

constexpr int NSAMP = 32768;
constexpr int DIM   = 2048;
constexpr int NCLS  = 512;
constexpr double EPS = 1e-6;
constexpr int NSLICE = 2;              // 2 slices x 1024 cols = 2048
constexpr int NPART  = NSLICE * NCLS;  // 1024 partial slots
constexpr int CAP    = 160;            // bucket capacity; max class count ~95 (+12 sigma)

// ws layout (byte offsets):
//   0      : int cursors[512]         (2048 B)   zeroed by memset; end value = count
//   8192   : int idx[512*160]         (327680 B) fixed-capacity buckets
//   344064 : double partQ[1024]       (8192 B)
//   352256 : double partT[1024]       (8192 B)

__global__ void __launch_bounds__(256) k_fill(const int* __restrict__ label,
                                              int* __restrict__ cursors,
                                              int* __restrict__ idx) {
    const int i = blockIdx.x * 256 + threadIdx.x;
    if (i < NSAMP) {
        const int c = label[i];
        const int p = atomicAdd(&cursors[c], 1);
        if (p < CAP) idx[c * CAP + p] = i;
    }
}

// 1024 single-wave blocks; block = (class via hash, 1024-col slice).
// Thread owns 16 cols as FOUR float4s at +0/+256/+512/+768, so the wave
// reads 1024 contiguous cols = 4 KB per row (best granularity: 1->2->4 KB
// measured -2.1/-0.7 us; 8 KB breaks the zero-communication T3 algebra).
// 4-row unroll keeps 16 KB/wave in flight. Whole-class rows in registers;
// zero global atomics.
__global__ void __launch_bounds__(64) k_main(const float* __restrict__ x,
                                             const int* __restrict__ cursors,
                                             const int* __restrict__ idx,
                                             double* __restrict__ partQ,
                                             double* __restrict__ partT) {
    const int b  = blockIdx.x;
    const int q0 = b >> 1;                       // 0..511
    const int s  = b & 1;                        // slice
    const int c  = (q0 * 331 + s * 57) & 511;    // bijective per slice
    const int cnt = min(cursors[c], CAP);
    __shared__ int idx_lds[CAP];
    for (int r = threadIdx.x; r < cnt; r += 64)
        idx_lds[r] = idx[c * CAP + r];
    __syncthreads();

    const float* xp = x + s * 1024 + threadIdx.x * 4;

    // 16 per-column sums (4 float4 banks) + 4 Q accumulators
    float4 S0 = {0,0,0,0}, S1 = {0,0,0,0}, S2 = {0,0,0,0}, S3 = {0,0,0,0};
    float Q0 = 0.f, Q1 = 0.f, Q2 = 0.f, Q3 = 0.f;

    int r = 0;
    for (; r + 4 <= cnt; r += 4) {
        float4 v[4][4];
        #pragma unroll
        for (int j = 0; j < 4; ++j) {
            const float* rp = xp + (size_t)idx_lds[r + j] * DIM;
            v[j][0] = *reinterpret_cast<const float4*>(rp);
            v[j][1] = *reinterpret_cast<const float4*>(rp + 256);
            v[j][2] = *reinterpret_cast<const float4*>(rp + 512);
            v[j][3] = *reinterpret_cast<const float4*>(rp + 768);
        }
        #pragma unroll
        for (int j = 0; j < 4; ++j) {
            S0.x += v[j][0].x; S0.y += v[j][0].y; S0.z += v[j][0].z; S0.w += v[j][0].w;
            Q0 += v[j][0].x*v[j][0].x + v[j][0].y*v[j][0].y + v[j][0].z*v[j][0].z + v[j][0].w*v[j][0].w;
            S1.x += v[j][1].x; S1.y += v[j][1].y; S1.z += v[j][1].z; S1.w += v[j][1].w;
            Q1 += v[j][1].x*v[j][1].x + v[j][1].y*v[j][1].y + v[j][1].z*v[j][1].z + v[j][1].w*v[j][1].w;
            S2.x += v[j][2].x; S2.y += v[j][2].y; S2.z += v[j][2].z; S2.w += v[j][2].w;
            Q2 += v[j][2].x*v[j][2].x + v[j][2].y*v[j][2].y + v[j][2].z*v[j][2].z + v[j][2].w*v[j][2].w;
            S3.x += v[j][3].x; S3.y += v[j][3].y; S3.z += v[j][3].z; S3.w += v[j][3].w;
            Q3 += v[j][3].x*v[j][3].x + v[j][3].y*v[j][3].y + v[j][3].z*v[j][3].z + v[j][3].w*v[j][3].w;
        }
    }
    for (; r < cnt; ++r) {
        const float* rp = xp + (size_t)idx_lds[r] * DIM;
        const float4 a  = *reinterpret_cast<const float4*>(rp);
        const float4 b2 = *reinterpret_cast<const float4*>(rp + 256);
        const float4 e  = *reinterpret_cast<const float4*>(rp + 512);
        const float4 f  = *reinterpret_cast<const float4*>(rp + 768);
        S0.x += a.x;  S0.y += a.y;  S0.z += a.z;  S0.w += a.w;
        Q0 += a.x*a.x + a.y*a.y + a.z*a.z + a.w*a.w;
        S1.x += b2.x; S1.y += b2.y; S1.z += b2.z; S1.w += b2.w;
        Q1 += b2.x*b2.x + b2.y*b2.y + b2.z*b2.z + b2.w*b2.w;
        S2.x += e.x;  S2.y += e.y;  S2.z += e.z;  S2.w += e.w;
        Q2 += e.x*e.x + e.y*e.y + e.z*e.z + e.w*e.w;
        S3.x += f.x;  S3.y += f.y;  S3.z += f.z;  S3.w += f.w;
        Q3 += f.x*f.x + f.y*f.y + f.z*f.z + f.w*f.w;
    }

    // distinct columns: square each column-sum separately
    double s2 = (double)S0.x*(double)S0.x + (double)S0.y*(double)S0.y
              + (double)S0.z*(double)S0.z + (double)S0.w*(double)S0.w
              + (double)S1.x*(double)S1.x + (double)S1.y*(double)S1.y
              + (double)S1.z*(double)S1.z + (double)S1.w*(double)S1.w
              + (double)S2.x*(double)S2.x + (double)S2.y*(double)S2.y
              + (double)S2.z*(double)S2.z + (double)S2.w*(double)S2.w
              + (double)S3.x*(double)S3.x + (double)S3.y*(double)S3.y
              + (double)S3.z*(double)S3.z + (double)S3.w*(double)S3.w;
    double q  = (double)(Q0 + Q1 + Q2 + Q3);

    #pragma unroll
    for (int off = 32; off > 0; off >>= 1) {
        q  += __shfl_down(q,  off, 64);
        s2 += __shfl_down(s2, off, 64);
    }
    if (threadIdx.x == 0) {
        const int slot = c * NSLICE + s;
        partQ[slot] = q;
        partT[slot] = (cnt > 0) ? (s2 / (double)cnt) : 0.0;
    }
}

__global__ void __launch_bounds__(256) k_final(const double* __restrict__ partQ,
                                               const double* __restrict__ partT,
                                               float* __restrict__ out) {
    double q = 0.0, t3 = 0.0;
    for (int i = threadIdx.x; i < NPART; i += 256) {
        q  += partQ[i];
        t3 += partT[i];
    }
    __shared__ double sq[256], st[256];
    sq[threadIdx.x] = q;
    st[threadIdx.x] = t3;
    __syncthreads();
    for (int o = 128; o > 0; o >>= 1) {
        if (threadIdx.x < o) {
            sq[threadIdx.x] += sq[threadIdx.x + o];
            st[threadIdx.x] += st[threadIdx.x + o];
        }
        __syncthreads();
    }
    if (threadIdx.x == 0) {
        // loss = (Q - T3)/N + D*eps^2  (the 2*eps linear term cancels exactly)
        out[0] = (float)((sq[0] - st[0]) / (double)NSAMP + (double)DIM * EPS * EPS);
    }
}

extern "C" void kernel_launch(void* const* d_in, const int* in_sizes, int n_in,
                              void* d_out, int out_size, void* d_ws, size_t ws_size,
                              hipStream_t stream) {
    const float* x     = (const float*)d_in[0];
    const int*   label = (const int*)d_in[1];
    float*       out   = (float*)d_out;

    char* ws = (char*)d_ws;
    int*    cursors = (int*)(ws + 0);
    int*    idx     = (int*)(ws + 8192);
    double* partQ   = (double*)(ws + 344064);
    double* partT   = (double*)(ws + 352256);

    hipMemsetAsync(cursors, 0, NCLS * sizeof(int), stream);
    hipLaunchKernelGGL(k_fill, dim3(NSAMP / 256), dim3(256), 0, stream,
                       label, cursors, idx);
    hipLaunchKernelGGL(k_main, dim3(NSLICE * NCLS), dim3(64), 0, stream,
                       x, cursors, idx, partQ, partT);
    hipLaunchKernelGGL(k_final, dim3(1), dim3(256), 0, stream, partQ, partT, out);
}